// Round 1
// baseline (436.470 us; speedup 1.0000x reference)
//
#include <hip/hip_runtime.h>

// EncoderDecoderLSTM on MI355X — R16: R15 base + (1) packed polynomial exp2
// replacing v_exp_f32 (VALUBusy accounting says trans ops are ~1/8 rate,
// ~16 cyc/wave64: 20 exp/wave-step = ~640 cyc/slot/SIMD = 34% of time;
// deg-4 pk-poly pair = 11 full-rate instrs ~22 cyc vs 32), rel err 4e-5
// << f16 h-plane noise 5e-4; (2) persistent f32x4 bias accumulators fed as
// MFMA C-operand in stepB (kills 16 v_mov/step). hw v_rcp kept: only 8/step
// and it sits on the serial R1->c->R2 chain. LDS write swizzle (~5% conflict
// cost) deferred to isolate numeric risk of the poly.
// Skeleton frozen since R12: 512 thr, grid 256 (1 block/CU, 2 waves/SIMD),
// waves 0-3 layer0 slot s / waves 4-7 layer1 slot s-1 (setprio(1) on B),
// one barrier/slot, static parity (unroll x2), h single f16 plane,
// single-f16 pre-scaled weights (1 MFMA/term), fused packed activation,
// c fp32 in regs, xv prefetched across the barrier.

typedef _Float16 f16x8 __attribute__((ext_vector_type(8)));
typedef float    f32x4 __attribute__((ext_vector_type(4)));
typedef float    f32x2 __attribute__((ext_vector_type(2)));

static constexpr int T_ENC = 365;
static constexpr int HZ    = 7;
static constexpr int BT    = 16;   // batch tile per block
static constexpr int HPAD  = 72;   // padded f16 row stride (144 B)

static constexpr float LOG2E  = 1.442695040888963f;
static constexpr float SCL_I  = -LOG2E;        // sigmoid gates: arg = -log2e * pre
static constexpr float SCL_G  = 2.0f * LOG2E;  // tanh gate:     arg = 2 log2e * pre

#if __has_builtin(__builtin_amdgcn_rcpf)
__device__ __forceinline__ float frcp(float x) { return __builtin_amdgcn_rcpf(x); }
#else
__device__ __forceinline__ float frcp(float x) { return 1.0f / x; }
#endif

// Packed polynomial exp2 over a row pair. n = rndne(x); f = x - n in
// [-0.5,0.5]; 2^f by deg-4 Taylor (rel err <= 4.2e-5); scale via v_ldexp_f32
// (graceful clamp for any n, matching hw v_exp over/underflow behavior).
// 11 full-rate instrs (2 v_rndne + 1 pk_sub + 4 pk_fma + 2 v_cvt_i32 +
// 2 v_ldexp) ~= 22 cyc vs 2 x v_exp_f32 ~= 32 cyc.
__device__ __forceinline__ f32x2 pexp2(f32x2 x) {
  const f32x2 c1 = {0.6931471805599453f, 0.6931471805599453f};
  const f32x2 c2 = {0.2402265069591007f, 0.2402265069591007f};
  const f32x2 c3 = {0.05550410866482158f, 0.05550410866482158f};
  const f32x2 c4 = {0.009618129107628477f, 0.009618129107628477f};
  const f32x2 one = {1.f, 1.f};
  f32x2 n;
  n.x = __builtin_rintf(x.x);
  n.y = __builtin_rintf(x.y);
  f32x2 f = x - n;                 // v_pk_add (neg)
  f32x2 p = c3 + f * c4;           // v_pk_fma
  p = c2 + f * p;
  p = c1 + f * p;
  p = one + f * p;
  f32x2 r;
  r.x = ldexpf(p.x, (int)n.x);     // v_cvt_i32_f32 + v_ldexp_f32
  r.y = ldexpf(p.y, (int)n.y);
  return r;
}

// acc += A * W  (both single-plane f16)
__device__ __forceinline__ f32x4 mm1(f16x8 a, f16x8 w, f32x4 acc) {
  return __builtin_amdgcn_mfma_f32_16x16x32_f16(a, w, acc, 0, 0, 0);
}

__global__ __launch_bounds__(512, 2)
void lstm_fused(const float* __restrict__ x,
                const float* __restrict__ eWih0, const float* __restrict__ eWhh0,
                const float* __restrict__ eb0,
                const float* __restrict__ eWih1, const float* __restrict__ eWhh1,
                const float* __restrict__ eb1,
                const float* __restrict__ dWih0, const float* __restrict__ dWhh0,
                const float* __restrict__ db0,
                const float* __restrict__ dWih1, const float* __restrict__ dWhh1,
                const float* __restrict__ db1,
                const float* __restrict__ fcW, const float* __restrict__ fcb,
                float* __restrict__ out)
{
  __shared__ __align__(16) float    xs[T_ENC * BT];                 // x transposed [t][b]
  __shared__ __align__(16) _Float16 h0s[2][BT * HPAD];              // h0, single f16 plane
  __shared__ __align__(16) _Float16 h1s[2][BT * HPAD];              // h1
  __shared__ __align__(16) float    dins[BT];

  const int tid  = threadIdx.x;
  const int lane = tid & 63;
  const int wv   = tid >> 6;        // wave 0..7; 0-3 = layer0 group, 4-7 = layer1 group
  const int wg   = wv & 3;          // index within group
  const int n    = lane & 15;       // tile col (gate row) / A-row (batch) index
  const int q    = lane >> 4;       // quad
  const int b0g  = blockIdx.x * BT;
  const int wbase = wg * 16 + n;    // D-layout j column for h writes
  const int nH   = n * HPAD;

#if __has_builtin(__builtin_amdgcn_s_setprio)
  if (wv >= 4) __builtin_amdgcn_s_setprio(1);   // B = long pole per slot
#endif

  // Stage x[b][t] -> xs[t][b]
  for (int i = tid; i < T_ENC * BT; i += 512) {
    int b = i / T_ENC;
    int t = i - b * T_ENC;
    xs[t * BT + b] = x[(b0g + b) * T_ENC + t];
  }
  for (int i = tid; i < 2 * BT * HPAD; i += 512) {
    ((_Float16*)h0s)[i] = (_Float16)0.f;
    ((_Float16*)h1s)[i] = (_Float16)0.f;
  }
  if (tid < BT) dins[tid] = 0.f;

  // Weight registers (single f16 plane of the PRE-SCALED weight):
  //   ti: 0=i (-log2e), 1=f (-log2e), 2=g (+2log2e), 3=o (-log2e)
  //   group A (layer0): WA = Whh0 ; wih0v = Wih0 col ; biasv = b0   (all scaled)
  //   group B (layer1): WA = Wih1 ; WB = Whh1 ; biasv = b1          (all scaled)
  f16x8 WA[4][2], WB[4][2];
  float biasv[4], wih0v[4];

  auto gscale = [&](int ti) { return (ti == 2) ? SCL_G : SCL_I; };

  auto cvtrow = [&](const float* p, float s, f16x8& w) {
    #pragma unroll
    for (int j = 0; j < 8; ++j) w[j] = (_Float16)(p[j] * s);
  };
  auto loadA = [&](const float* Wih0_, const float* Whh0_, const float* b0_) {
    #pragma unroll
    for (int ti = 0; ti < 4; ++ti) {
      const float s = gscale(ti);
      const int r = (ti * 4 + wg) * 16 + n;
      biasv[ti] = b0_[r] * s;
      wih0v[ti] = Wih0_[r] * s;
      #pragma unroll
      for (int kc = 0; kc < 2; ++kc)
        cvtrow(Whh0_ + r * 64 + kc * 32 + q * 8, s, WA[ti][kc]);
    }
  };
  auto loadB = [&](const float* Wih1_, const float* Whh1_, const float* b1_) {
    #pragma unroll
    for (int ti = 0; ti < 4; ++ti) {
      const float s = gscale(ti);
      const int r = (ti * 4 + wg) * 16 + n;
      biasv[ti] = b1_[r] * s;
      #pragma unroll
      for (int kc = 0; kc < 2; ++kc) {
        cvtrow(Wih1_ + r * 64 + kc * 32 + q * 8, s, WA[ti][kc]);
        cvtrow(Whh1_ + r * 64 + kc * 32 + q * 8, s, WB[ti][kc]);
      }
    }
  };

  // Persistent bias accumulators for stepB: fed directly as the MFMA
  // C-operand (D != C), eliminating the 16 v_mov broadcast per B-step.
  f32x4 biasq[4];
  auto mkbias = [&]() {
    #pragma unroll
    for (int ti = 0; ti < 4; ++ti) {
      #pragma unroll
      for (int r = 0; r < 4; ++r) biasq[ti][r] = biasv[ti];
    }
  };

  if (wv < 4) { loadA(eWih0, eWhh0, eb0); }
  else        { loadB(eWih1, eWhh1, eb1); mkbias(); }

  f32x2 cp[2] = {{0.f, 0.f}, {0.f, 0.f}};   // c-state, row pairs (0,1),(2,3)

  // Packed fused activation for a ROW PAIR. Inputs are pre-scaled exp2 args:
  //   a0 = -K*i, a1 = -K*f, a2 = 2K*g, a3 = -K*o (2 rows each).
  // exp2 via pexp2 (full-rate poly); rcp stays hw (serial R1->c->R2 chain).
  auto act2 = [&](f32x2 a0, f32x2 a1, f32x2 a2, f32x2 a3, f32x2& c) -> f32x2 {
    f32x2 ei = pexp2(a0);
    f32x2 ef = pexp2(a1);
    f32x2 eg = pexp2(a2);
    f32x2 eo = pexp2(a3);
    const f32x2 one = {1.f, 1.f};
    f32x2 di = one + ei, df = one + ef, dg = one + eg, dd = one + eo;
    f32x2 ng = eg - one;
    f32x2 pig = di * dg;
    f32x2 t1 = pig * df;
    f32x2 R1; R1.x = frcp(t1.x); R1.y = frcp(t1.y);
    f32x2 sf = R1 * pig;                 // sig(f)
    f32x2 B  = ng * R1 * df;             // sig(i)*tanh(g)
    c = sf * c + B;                      // v_pk_fma
    const f32x2 sclg = {SCL_G, SCL_G};
    const f32x2 cap  = {20.f, 20.f};
    f32x2 ca = sclg * c;                 // v_pk_mul
    ca.x = fminf(ca.x, cap.x); ca.y = fminf(ca.y, cap.y);   // v_pk_min
    f32x2 ec = pexp2(ca);
    f32x2 dc = one + ec, nc = ec - one;
    f32x2 t2 = dc * dd;
    f32x2 R2; R2.x = frcp(t2.x); R2.y = frcp(t2.y);
    return nc * R2;                      // sig(o)*tanh(c)
  };

  // Shared epilogue: act on 4 rows (2 packed pairs) + h publish.
  auto epilogue = [&](const f32x4* g, _Float16* O) {
    #pragma unroll
    for (int pr = 0; pr < 2; ++pr) {
      f32x2 a0 = {g[0][2 * pr], g[0][2 * pr + 1]};
      f32x2 a1 = {g[1][2 * pr], g[1][2 * pr + 1]};
      f32x2 a2 = {g[2][2 * pr], g[2][2 * pr + 1]};
      f32x2 a3 = {g[3][2 * pr], g[3][2 * pr + 1]};
      f32x2 h2 = act2(a0, a1, a2, a3, cp[pr]);
      O[(q * 4 + 2 * pr) * HPAD + wbase]     = (_Float16)h2.x;
      O[(q * 4 + 2 * pr + 1) * HPAD + wbase] = (_Float16)h2.y;
    }
  };

  // layer0 step: args = bias + x*wih0 + h0 @ Whh0^T (pre-scaled).
  // Gate prologue packed: 8 v_pk_fma instead of 16 v_fma.
  auto stepA = [&](const _Float16* H, _Float16* O, f32x4 xv) {
    const _Float16* hp = H + nH;
    f16x8 a0 = *(const f16x8*)(hp + q * 8);
    f16x8 a1 = *(const f16x8*)(hp + 32 + q * 8);
    f32x4 g[4];
    #pragma unroll
    for (int ti = 0; ti < 4; ++ti) {
      const f32x2 wb = {wih0v[ti], wih0v[ti]};
      const f32x2 bb = {biasv[ti], biasv[ti]};
      f32x2 lo = {xv[0], xv[1]};
      f32x2 hi = {xv[2], xv[3]};
      lo = lo * wb + bb;                 // v_pk_fma
      hi = hi * wb + bb;
      f32x4 a = {lo.x, lo.y, hi.x, hi.y};
      a = mm1(a0, WA[ti][0], a);
      a = mm1(a1, WA[ti][1], a);
      g[ti] = a;
    }
    epilogue(g, O);
  };

  // layer1 step: args = bias + h0 @ Wih1^T + h1 @ Whh1^T (pre-scaled).
  // Accumulators seeded from persistent biasq via the MFMA C-operand.
  auto stepB = [&](const _Float16* H0, const _Float16* H1, _Float16* O) {
    const _Float16* p0 = H0 + nH;
    const _Float16* p1 = H1 + nH;
    f16x8 b0 = *(const f16x8*)(p0 + q * 8);
    f16x8 b1 = *(const f16x8*)(p0 + 32 + q * 8);
    f16x8 a0 = *(const f16x8*)(p1 + q * 8);
    f16x8 a1 = *(const f16x8*)(p1 + 32 + q * 8);
    f32x4 g[4];
    #pragma unroll
    for (int ti = 0; ti < 4; ++ti) {
      f32x4 a = mm1(b0, WA[ti][0], biasq[ti]);
      a = mm1(b1, WA[ti][1], a);
      a = mm1(a0, WB[ti][0], a);
      a = mm1(a1, WB[ti][1], a);
      g[ti] = a;
    }
    epilogue(g, O);
  };

  __syncthreads();

  // ---- encoder, unrolled x2 with static parity ----
  // slot s: A reads h0[(s&1)^1] writes h0[s&1];
  // B (t=s-1) reads h0[t&1], h1[(t&1)^1], writes h1[t&1].

  f32x4 xv_next;
  // s = 0 (even): A only. h0[1] is zeros.
  if (wv < 4) {
    f32x4 xv = *(const f32x4*)(xs + q * 4);
    stepA(h0s[1], h0s[0], xv);
    xv_next = *(const f32x4*)(xs + BT + q * 4);   // prefetch s=1 (xs read-only)
  }
  __syncthreads();

  // s = 1..364 as 182 (odd, even) pairs — both groups always active.
  for (int s = 1; s <= 363; s += 2) {
    // slot s (odd): A h0[0]->h0[1] ; B(t even) h0[0],h1[1] -> h1[0]
    if (wv < 4) {
      stepA(h0s[0], h0s[1], xv_next);
      xv_next = *(const f32x4*)(xs + (s + 1) * BT + q * 4);   // prefetch s+1
    } else {
      stepB(h0s[0], h1s[1], h1s[0]);
    }
    __syncthreads();
    // slot s+1 (even): A h0[1]->h0[0] ; B(t odd) h0[1],h1[0] -> h1[1]
    if (wv < 4) {
      stepA(h0s[1], h0s[0], xv_next);
      if (s + 2 <= 364)
        xv_next = *(const f32x4*)(xs + (s + 2) * BT + q * 4); // prefetch s+2
    } else {
      stepB(h0s[1], h1s[0], h1s[1]);
    }
    __syncthreads();
  }

  // s = 365 (odd): A loads decoder weights (idle slot); B(t=364 even):
  // h0[0], h1[1] -> h1[0].
  if (wv < 4) loadA(dWih0, dWhh0, db0);
  else        stepB(h0s[0], h1s[1], h1s[0]);
  __syncthreads();

  // ---- decoder ---- (latest h0, h1 live in parity-0 buffers)
  if (wv >= 4) { loadB(dWih1, dWhh1, db1); mkbias(); }
  float fcw[16];
  #pragma unroll
  for (int j = 0; j < 16; ++j) fcw[j] = fcW[q * 16 + j];
  const float fcb0 = fcb[0];

  #pragma unroll 1
  for (int hz = 0; hz < HZ; ++hz) {
    const int p = hz & 1;           // latest state parity at step entry
    if (wv < 4) {
      f32x4 dv = *(const f32x4*)(dins + q * 4);
      stepA(h0s[p], h0s[1 - p], dv);
    }
    __syncthreads();
    if (wv >= 4) {
      stepB(h0s[1 - p], h1s[p], h1s[1 - p]);
    }
    __syncthreads();
    if (wv == 0) {
      const _Float16* Hh = h1s[1 - p];
      f16x8 hh0 = *(const f16x8*)(Hh + nH + q * 16);
      f16x8 hh1 = *(const f16x8*)(Hh + nH + q * 16 + 8);
      float pacc = 0.f;
      #pragma unroll
      for (int j = 0; j < 8; ++j) pacc += fcw[j] * (float)hh0[j];
      #pragma unroll
      for (int j = 0; j < 8; ++j) pacc += fcw[8 + j] * (float)hh1[j];
      pacc += __shfl_down(pacc, 32);
      pacc += __shfl_down(pacc, 16);
      if (lane < BT) {
        pacc += fcb0;
        out[(b0g + lane) * HZ + hz] = pacc;
        dins[lane] = pacc;
      }
    }
    __syncthreads();
  }
}

extern "C" void kernel_launch(void* const* d_in, const int* in_sizes, int n_in,
                              void* d_out, int out_size, void* d_ws, size_t ws_size,
                              hipStream_t stream) {
  (void)in_sizes; (void)n_in; (void)d_ws; (void)ws_size; (void)out_size;
  const float* x     = (const float*)d_in[0];
  const float* eWih0 = (const float*)d_in[1];
  const float* eWhh0 = (const float*)d_in[2];
  const float* eb0   = (const float*)d_in[3];
  const float* eWih1 = (const float*)d_in[4];
  const float* eWhh1 = (const float*)d_in[5];
  const float* eb1   = (const float*)d_in[6];
  const float* dWih0 = (const float*)d_in[7];
  const float* dWhh0 = (const float*)d_in[8];
  const float* db0   = (const float*)d_in[9];
  const float* dWih1 = (const float*)d_in[10];
  const float* dWhh1 = (const float*)d_in[11];
  const float* db1   = (const float*)d_in[12];
  const float* fcW   = (const float*)d_in[13];
  const float* fcb   = (const float*)d_in[14];
  float* out = (float*)d_out;

  dim3 grid(4096 / BT);   // 256 blocks = 1/CU
  dim3 block(512);        // 8 waves: 4 layer0 + 4 layer1
  hipLaunchKernelGGL(lstm_fused, grid, block, 0, stream,
                     x, eWih0, eWhh0, eb0, eWih1, eWhh1, eb1,
                     dWih0, dWhh0, db0, dWih1, dWhh1, db1, fcW, fcb, out);
}

// Round 2
// 325.943 us; speedup vs baseline: 1.3391x; 1.3391x over previous
//
#include <hip/hip_runtime.h>

// EncoderDecoderLSTM on MI355X — R17: revert R16 poly-exp2 (FAILED: +813
// cyc/slot for +360 issue cyc -> hw v_exp is cheap, trans pipe overlaps;
// issue amplification ~2.3x confirms issue-reduction pays double).
// New: OPERAND-SWAPPED MFMA  D = W * h^T  (A/B fragment lane maps are
// symmetric, so W and h fragments keep the same bytes; only D transposes:
// row=gate-unit, col=batch). Payoff:
//   (1) each lane's 4 h outputs = 4 CONSECUTIVE hidden units of one batch
//       row -> h publish is ONE aligned ds_write_b64 instead of 4 scattered
//       ds_write_b16 (kills the store-side bank conflicts, ~100 cyc/slot/CU
//       of the 9.84M SQ_LDS_BANK_CONFLICT).
//   (2) bias varies along D rows -> f32x4 biasq fed as the MFMA C-operand:
//       zero-issue bias (kills 16 v_mov/B-step, acc-assembly movs in A).
//   (3) stepA x-term is now a lane-scalar broadcast: ci = biasq + xb*wih0q
//       (2 v_pk_fma off the MFMA->act chain); x prefetch b128 -> b32.
// Reads, activation algebra (5 exp + 2 rcp / row, hw trans), c-in-regs,
// decoder, h-plane layout all unchanged.
// Skeleton frozen since R12: 512 thr, grid 256 (1 block/CU, 2 waves/SIMD),
// waves 0-3 layer0 slot s / waves 4-7 layer1 slot s-1 (setprio(1) on B),
// one barrier/slot, static parity (unroll x2), h single f16 plane,
// single-f16 pre-scaled weights (1 MFMA/term), fused packed activation,
// xb prefetched across the barrier.

typedef _Float16 f16x8 __attribute__((ext_vector_type(8)));
typedef _Float16 f16x4 __attribute__((ext_vector_type(4)));
typedef float    f32x4 __attribute__((ext_vector_type(4)));
typedef float    f32x2 __attribute__((ext_vector_type(2)));

static constexpr int T_ENC = 365;
static constexpr int HZ    = 7;
static constexpr int BT    = 16;   // batch tile per block
static constexpr int HPAD  = 72;   // padded f16 row stride (144 B)

static constexpr float LOG2E  = 1.442695040888963f;
static constexpr float SCL_I  = -LOG2E;        // sigmoid gates: arg = -log2e * pre
static constexpr float SCL_G  = 2.0f * LOG2E;  // tanh gate:     arg = 2 log2e * pre

#if __has_builtin(__builtin_amdgcn_exp2f)
__device__ __forceinline__ float fexp2(float x) { return __builtin_amdgcn_exp2f(x); }
#else
__device__ __forceinline__ float fexp2(float x) { return __exp2f(x); }
#endif
#if __has_builtin(__builtin_amdgcn_rcpf)
__device__ __forceinline__ float frcp(float x) { return __builtin_amdgcn_rcpf(x); }
#else
__device__ __forceinline__ float frcp(float x) { return 1.0f / x; }
#endif

// acc += W * A^T : A-operand = weight fragment, B-operand = h fragment.
// (Same register bytes as the pre-swap kernel; D transposed.)
__device__ __forceinline__ f32x4 mm1(f16x8 w, f16x8 a, f32x4 acc) {
  return __builtin_amdgcn_mfma_f32_16x16x32_f16(w, a, acc, 0, 0, 0);
}

__global__ __launch_bounds__(512, 2)
void lstm_fused(const float* __restrict__ x,
                const float* __restrict__ eWih0, const float* __restrict__ eWhh0,
                const float* __restrict__ eb0,
                const float* __restrict__ eWih1, const float* __restrict__ eWhh1,
                const float* __restrict__ eb1,
                const float* __restrict__ dWih0, const float* __restrict__ dWhh0,
                const float* __restrict__ db0,
                const float* __restrict__ dWih1, const float* __restrict__ dWhh1,
                const float* __restrict__ db1,
                const float* __restrict__ fcW, const float* __restrict__ fcb,
                float* __restrict__ out)
{
  __shared__ __align__(16) float    xs[T_ENC * BT];                 // x transposed [t][b]
  __shared__ __align__(16) _Float16 h0s[2][BT * HPAD];              // h0, single f16 plane
  __shared__ __align__(16) _Float16 h1s[2][BT * HPAD];              // h1
  __shared__ __align__(16) float    dins[BT];

  const int tid  = threadIdx.x;
  const int lane = tid & 63;
  const int wv   = tid >> 6;        // wave 0..7; 0-3 = layer0 group, 4-7 = layer1 group
  const int wg   = wv & 3;          // index within group
  const int n    = lane & 15;       // D col = batch row ; weight-fragment A-row
  const int q    = lane >> 4;       // quad: D rows 4q..4q+3 ; k-chunk for frags
  const int b0g  = blockIdx.x * BT;
  const int nH   = n * HPAD;
  const int cbase = (wg << 4) + (q << 2);   // hidden-col base this lane owns (4 units)

#if __has_builtin(__builtin_amdgcn_s_setprio)
  if (wv >= 4) __builtin_amdgcn_s_setprio(1);   // B = long pole per slot
#endif

  // Stage x[b][t] -> xs[t][b]
  for (int i = tid; i < T_ENC * BT; i += 512) {
    int b = i / T_ENC;
    int t = i - b * T_ENC;
    xs[t * BT + b] = x[(b0g + b) * T_ENC + t];
  }
  for (int i = tid; i < 2 * BT * HPAD; i += 512) {
    ((_Float16*)h0s)[i] = (_Float16)0.f;
    ((_Float16*)h1s)[i] = (_Float16)0.f;
  }
  if (tid < BT) dins[tid] = 0.f;

  // Weight registers (single f16 plane of the PRE-SCALED weight):
  //   ti: 0=i (-log2e), 1=f (-log2e), 2=g (+2log2e), 3=o (-log2e)
  //   group A (layer0): WA = Whh0 ; wih0q = Wih0 rows (D-layout) ; biasq = b0
  //   group B (layer1): WA = Wih1 ; WB = Whh1 ; biasq = b1       (all scaled)
  // Weight FRAGMENT rows use n (A-operand row); bias/wih0 use the D-row
  // axis 4q+rr (they ride the accumulator).
  f16x8 WA[4][2], WB[4][2];
  f32x4 biasq[4], wih0q[4];

  auto gscale = [&](int ti) { return (ti == 2) ? SCL_G : SCL_I; };

  auto cvtrow = [&](const float* p, float s, f16x8& w) {
    #pragma unroll
    for (int j = 0; j < 8; ++j) w[j] = (_Float16)(p[j] * s);
  };
  auto loadA = [&](const float* Wih0_, const float* Whh0_, const float* b0_) {
    #pragma unroll
    for (int ti = 0; ti < 4; ++ti) {
      const float s = gscale(ti);
      const int rw = (ti * 4 + wg) * 16 + n;        // weight fragment row
      const int rq = (ti * 4 + wg) * 16 + (q << 2); // D-row base for bias/wih0
      #pragma unroll
      for (int rr = 0; rr < 4; ++rr) {
        biasq[ti][rr] = b0_[rq + rr] * s;
        wih0q[ti][rr] = Wih0_[rq + rr] * s;
      }
      #pragma unroll
      for (int kc = 0; kc < 2; ++kc)
        cvtrow(Whh0_ + rw * 64 + kc * 32 + q * 8, s, WA[ti][kc]);
    }
  };
  auto loadB = [&](const float* Wih1_, const float* Whh1_, const float* b1_) {
    #pragma unroll
    for (int ti = 0; ti < 4; ++ti) {
      const float s = gscale(ti);
      const int rw = (ti * 4 + wg) * 16 + n;
      const int rq = (ti * 4 + wg) * 16 + (q << 2);
      #pragma unroll
      for (int rr = 0; rr < 4; ++rr) biasq[ti][rr] = b1_[rq + rr] * s;
      #pragma unroll
      for (int kc = 0; kc < 2; ++kc) {
        cvtrow(Wih1_ + rw * 64 + kc * 32 + q * 8, s, WA[ti][kc]);
        cvtrow(Whh1_ + rw * 64 + kc * 32 + q * 8, s, WB[ti][kc]);
      }
    }
  };

  if (wv < 4) loadA(eWih0, eWhh0, eb0);
  else        loadB(eWih1, eWhh1, eb1);

  // c-state: lane owns (batch n, hidden cbase+0..3), pairs (0,1),(2,3).
  f32x2 cp[2] = {{0.f, 0.f}, {0.f, 0.f}};

  // Packed fused activation for a ROW PAIR (2 hidden units, same batch).
  // Inputs are pre-scaled exp2 args: a0=-K*i, a1=-K*f, a2=2K*g, a3=-K*o.
  auto act2 = [&](f32x2 a0, f32x2 a1, f32x2 a2, f32x2 a3, f32x2& c) -> f32x2 {
    f32x2 ei, ef, eg, eo;
    ei.x = fexp2(a0.x); ei.y = fexp2(a0.y);
    ef.x = fexp2(a1.x); ef.y = fexp2(a1.y);
    eg.x = fexp2(a2.x); eg.y = fexp2(a2.y);
    eo.x = fexp2(a3.x); eo.y = fexp2(a3.y);
    const f32x2 one = {1.f, 1.f};
    f32x2 di = one + ei, df = one + ef, dg = one + eg, dd = one + eo;
    f32x2 ng = eg - one;
    f32x2 pig = di * dg;
    f32x2 t1 = pig * df;
    f32x2 R1; R1.x = frcp(t1.x); R1.y = frcp(t1.y);
    f32x2 sf = R1 * pig;                 // sig(f)
    f32x2 B  = ng * R1 * df;             // sig(i)*tanh(g)
    c = sf * c + B;                      // v_pk_fma
    const f32x2 sclg = {SCL_G, SCL_G};
    const f32x2 cap  = {20.f, 20.f};
    f32x2 ca = sclg * c;                 // v_pk_mul
    ca.x = fminf(ca.x, cap.x); ca.y = fminf(ca.y, cap.y);   // v_pk_min
    f32x2 ec; ec.x = fexp2(ca.x); ec.y = fexp2(ca.y);
    f32x2 dc = one + ec, nc = ec - one;
    f32x2 t2 = dc * dd;
    f32x2 R2; R2.x = frcp(t2.x); R2.y = frcp(t2.y);
    return nc * R2;                      // sig(o)*tanh(c)
  };

  // Shared epilogue: act on 4 D-rows (2 packed pairs) + single b64 h publish
  // (4 consecutive hidden units at row n, col cbase).
  auto epilogue = [&](const f32x4* g, _Float16* O) {
    f32x2 h2[2];
    #pragma unroll
    for (int pr = 0; pr < 2; ++pr) {
      f32x2 a0 = {g[0][2 * pr], g[0][2 * pr + 1]};
      f32x2 a1 = {g[1][2 * pr], g[1][2 * pr + 1]};
      f32x2 a2 = {g[2][2 * pr], g[2][2 * pr + 1]};
      f32x2 a3 = {g[3][2 * pr], g[3][2 * pr + 1]};
      h2[pr] = act2(a0, a1, a2, a3, cp[pr]);
    }
    f16x4 hv;
    hv[0] = (_Float16)h2[0].x; hv[1] = (_Float16)h2[0].y;
    hv[2] = (_Float16)h2[1].x; hv[3] = (_Float16)h2[1].y;
    *(f16x4*)(O + nH + cbase) = hv;      // aligned 8B ds_write_b64
  };

  // layer0 step: D = bias + x(*)wih0 + Whh0 * h0^T (pre-scaled).
  // ci = biasq + xb*wih0q computed while the ds_reads are in flight,
  // then fed as the MFMA C-operand (off the MFMA->act critical path).
  auto stepA = [&](const _Float16* H, _Float16* O, float xb) {
    const _Float16* hp = H + nH;
    f16x8 a0 = *(const f16x8*)(hp + q * 8);
    f16x8 a1 = *(const f16x8*)(hp + 32 + q * 8);
    const f32x4 xbv = {xb, xb, xb, xb};
    f32x4 g[4];
    #pragma unroll
    for (int ti = 0; ti < 4; ++ti) {
      f32x4 ci = biasq[ti] + xbv * wih0q[ti];   // 2 v_pk_fma
      f32x4 a = mm1(WA[ti][0], a0, ci);
      a = mm1(WA[ti][1], a1, a);
      g[ti] = a;
    }
    epilogue(g, O);
  };

  // layer1 step: D = bias + Wih1 * h0^T + Whh1 * h1^T (pre-scaled).
  // Accumulators seeded from biasq via the MFMA C-operand (zero issue).
  auto stepB = [&](const _Float16* H0, const _Float16* H1, _Float16* O) {
    const _Float16* p0 = H0 + nH;
    const _Float16* p1 = H1 + nH;
    f16x8 b0 = *(const f16x8*)(p0 + q * 8);
    f16x8 b1 = *(const f16x8*)(p0 + 32 + q * 8);
    f16x8 a0 = *(const f16x8*)(p1 + q * 8);
    f16x8 a1 = *(const f16x8*)(p1 + 32 + q * 8);
    f32x4 g[4];
    #pragma unroll
    for (int ti = 0; ti < 4; ++ti) {
      f32x4 a = mm1(WA[ti][0], b0, biasq[ti]);
      a = mm1(WA[ti][1], b1, a);
      a = mm1(WB[ti][0], a0, a);
      a = mm1(WB[ti][1], a1, a);
      g[ti] = a;
    }
    epilogue(g, O);
  };

  __syncthreads();

  // ---- encoder, unrolled x2 with static parity ----
  // slot s: A reads h0[(s&1)^1] writes h0[s&1];
  // B (t=s-1) reads h0[t&1], h1[(t&1)^1], writes h1[t&1].

  float xb_next;
  // s = 0 (even): A only. h0[1] is zeros.
  if (wv < 4) {
    float xb = xs[n];
    stepA(h0s[1], h0s[0], xb);
    xb_next = xs[BT + n];               // prefetch s=1 (xs read-only)
  }
  __syncthreads();

  // s = 1..364 as 182 (odd, even) pairs — both groups always active.
  for (int s = 1; s <= 363; s += 2) {
    // slot s (odd): A h0[0]->h0[1] ; B(t even) h0[0],h1[1] -> h1[0]
    if (wv < 4) {
      stepA(h0s[0], h0s[1], xb_next);
      xb_next = xs[(s + 1) * BT + n];   // prefetch s+1
    } else {
      stepB(h0s[0], h1s[1], h1s[0]);
    }
    __syncthreads();
    // slot s+1 (even): A h0[1]->h0[0] ; B(t odd) h0[1],h1[0] -> h1[1]
    if (wv < 4) {
      stepA(h0s[1], h0s[0], xb_next);
      if (s + 2 <= 364)
        xb_next = xs[(s + 2) * BT + n]; // prefetch s+2
    } else {
      stepB(h0s[1], h1s[0], h1s[1]);
    }
    __syncthreads();
  }

  // s = 365 (odd): A loads decoder weights (idle slot); B(t=364 even):
  // h0[0], h1[1] -> h1[0].
  if (wv < 4) loadA(dWih0, dWhh0, db0);
  else        stepB(h0s[0], h1s[1], h1s[0]);
  __syncthreads();

  // ---- decoder ---- (latest h0, h1 live in parity-0 buffers)
  if (wv >= 4) loadB(dWih1, dWhh1, db1);
  float fcw[16];
  #pragma unroll
  for (int j = 0; j < 16; ++j) fcw[j] = fcW[q * 16 + j];
  const float fcb0 = fcb[0];

  #pragma unroll 1
  for (int hz = 0; hz < HZ; ++hz) {
    const int p = hz & 1;           // latest state parity at step entry
    if (wv < 4) {
      stepA(h0s[p], h0s[1 - p], dins[n]);
    }
    __syncthreads();
    if (wv >= 4) {
      stepB(h0s[1 - p], h1s[p], h1s[1 - p]);
    }
    __syncthreads();
    if (wv == 0) {
      const _Float16* Hh = h1s[1 - p];
      f16x8 hh0 = *(const f16x8*)(Hh + nH + q * 16);
      f16x8 hh1 = *(const f16x8*)(Hh + nH + q * 16 + 8);
      float pacc = 0.f;
      #pragma unroll
      for (int j = 0; j < 8; ++j) pacc += fcw[j] * (float)hh0[j];
      #pragma unroll
      for (int j = 0; j < 8; ++j) pacc += fcw[8 + j] * (float)hh1[j];
      pacc += __shfl_down(pacc, 32);
      pacc += __shfl_down(pacc, 16);
      if (lane < BT) {
        pacc += fcb0;
        out[(b0g + lane) * HZ + hz] = pacc;
        dins[lane] = pacc;
      }
    }
    __syncthreads();
  }
}

extern "C" void kernel_launch(void* const* d_in, const int* in_sizes, int n_in,
                              void* d_out, int out_size, void* d_ws, size_t ws_size,
                              hipStream_t stream) {
  (void)in_sizes; (void)n_in; (void)d_ws; (void)ws_size; (void)out_size;
  const float* x     = (const float*)d_in[0];
  const float* eWih0 = (const float*)d_in[1];
  const float* eWhh0 = (const float*)d_in[2];
  const float* eb0   = (const float*)d_in[3];
  const float* eWih1 = (const float*)d_in[4];
  const float* eWhh1 = (const float*)d_in[5];
  const float* eb1   = (const float*)d_in[6];
  const float* dWih0 = (const float*)d_in[7];
  const float* dWhh0 = (const float*)d_in[8];
  const float* db0   = (const float*)d_in[9];
  const float* dWih1 = (const float*)d_in[10];
  const float* dWhh1 = (const float*)d_in[11];
  const float* db1   = (const float*)d_in[12];
  const float* fcW   = (const float*)d_in[13];
  const float* fcb   = (const float*)d_in[14];
  float* out = (float*)d_out;

  dim3 grid(4096 / BT);   // 256 blocks = 1/CU
  dim3 block(512);        // 8 waves: 4 layer0 + 4 layer1
  hipLaunchKernelGGL(lstm_fused, grid, block, 0, stream,
                     x, eWih0, eWhh0, eb0, eWih1, eWhh1, eb1,
                     dWih0, dWhh0, db0, dWih1, dWhh1, db1, fcW, fcb, out);
}

// Round 3
// 314.394 us; speedup vs baseline: 1.3883x; 1.0367x over previous
//
#include <hip/hip_runtime.h>

// EncoderDecoderLSTM on MI355X — R18: R17 base + act2 SERIAL-CHAIN
// restructure. Model (fits R14/R16/R17): ops in the activation dependency
// chain cost latency (~6cyc), not issue (2cyc) — R16's +90 serial ops cost
// +849 cyc/slot. So shorten the chain, not just the op count:
//   c_new = R1*(pig*c + ng*df)  with s = (di*c)*dg + fma(eg,df,-df)
//           precomputed during rcp flight -> 1 mul after R1 (was 2 levels)
//   ca    = min(R1*(SCLG*s), 20) -> sg precomputed (was 2 more levels)
//   t1    = (di*df)*dg           -> depth from late eg: 3 -> 2
//   t2    = fma(ec, dd, dd)      -> post-ec: 1 level saved, nc parallel
// ~4 serial levels removed per pair; 16 pk-ops (was 17); exp/rcp unchanged
// (5 exp + 2 rcp per row = algebraic floor). Reassociation = 1-2ulp f32,
// masked by f16 h quantization. stepB MFMA-split considered and DROPPED
// (4 independent depth-4 chains already feed the pipe; +8 adds > 1 hop).
// R17 carryovers: operand-swapped MFMA D = W*h^T (b64 h-store, biasq via
// MFMA C-operand, lane-scalar x term). LDS at floor: reads 8-lane/quad
// uniform (conflict-free), b64 stores BW-floor (counter noise only).
// Skeleton frozen since R12: 512 thr, grid 256 (1 block/CU, 2 waves/SIMD),
// waves 0-3 layer0 slot s / waves 4-7 layer1 slot s-1 (setprio(1) on B),
// one barrier/slot, static parity (unroll x2), h single f16 plane,
// single-f16 pre-scaled weights (1 MFMA/term), c fp32 in regs,
// xb prefetched across the barrier.

typedef _Float16 f16x8 __attribute__((ext_vector_type(8)));
typedef _Float16 f16x4 __attribute__((ext_vector_type(4)));
typedef float    f32x4 __attribute__((ext_vector_type(4)));
typedef float    f32x2 __attribute__((ext_vector_type(2)));

static constexpr int T_ENC = 365;
static constexpr int HZ    = 7;
static constexpr int BT    = 16;   // batch tile per block
static constexpr int HPAD  = 72;   // padded f16 row stride (144 B)

static constexpr float LOG2E  = 1.442695040888963f;
static constexpr float SCL_I  = -LOG2E;        // sigmoid gates: arg = -log2e * pre
static constexpr float SCL_G  = 2.0f * LOG2E;  // tanh gate:     arg = 2 log2e * pre

#if __has_builtin(__builtin_amdgcn_exp2f)
__device__ __forceinline__ float fexp2(float x) { return __builtin_amdgcn_exp2f(x); }
#else
__device__ __forceinline__ float fexp2(float x) { return __exp2f(x); }
#endif
#if __has_builtin(__builtin_amdgcn_rcpf)
__device__ __forceinline__ float frcp(float x) { return __builtin_amdgcn_rcpf(x); }
#else
__device__ __forceinline__ float frcp(float x) { return 1.0f / x; }
#endif

// acc += W * A^T : A-operand = weight fragment, B-operand = h fragment.
__device__ __forceinline__ f32x4 mm1(f16x8 w, f16x8 a, f32x4 acc) {
  return __builtin_amdgcn_mfma_f32_16x16x32_f16(w, a, acc, 0, 0, 0);
}

__global__ __launch_bounds__(512, 2)
void lstm_fused(const float* __restrict__ x,
                const float* __restrict__ eWih0, const float* __restrict__ eWhh0,
                const float* __restrict__ eb0,
                const float* __restrict__ eWih1, const float* __restrict__ eWhh1,
                const float* __restrict__ eb1,
                const float* __restrict__ dWih0, const float* __restrict__ dWhh0,
                const float* __restrict__ db0,
                const float* __restrict__ dWih1, const float* __restrict__ dWhh1,
                const float* __restrict__ db1,
                const float* __restrict__ fcW, const float* __restrict__ fcb,
                float* __restrict__ out)
{
  __shared__ __align__(16) float    xs[T_ENC * BT];                 // x transposed [t][b]
  __shared__ __align__(16) _Float16 h0s[2][BT * HPAD];              // h0, single f16 plane
  __shared__ __align__(16) _Float16 h1s[2][BT * HPAD];              // h1
  __shared__ __align__(16) float    dins[BT];

  const int tid  = threadIdx.x;
  const int lane = tid & 63;
  const int wv   = tid >> 6;        // wave 0..7; 0-3 = layer0 group, 4-7 = layer1 group
  const int wg   = wv & 3;          // index within group
  const int n    = lane & 15;       // D col = batch row ; weight-fragment A-row
  const int q    = lane >> 4;       // quad: D rows 4q..4q+3 ; k-chunk for frags
  const int b0g  = blockIdx.x * BT;
  const int nH   = n * HPAD;
  const int cbase = (wg << 4) + (q << 2);   // hidden-col base this lane owns (4 units)

#if __has_builtin(__builtin_amdgcn_s_setprio)
  if (wv >= 4) __builtin_amdgcn_s_setprio(1);   // B = long pole per slot
#endif

  // Stage x[b][t] -> xs[t][b]
  for (int i = tid; i < T_ENC * BT; i += 512) {
    int b = i / T_ENC;
    int t = i - b * T_ENC;
    xs[t * BT + b] = x[(b0g + b) * T_ENC + t];
  }
  for (int i = tid; i < 2 * BT * HPAD; i += 512) {
    ((_Float16*)h0s)[i] = (_Float16)0.f;
    ((_Float16*)h1s)[i] = (_Float16)0.f;
  }
  if (tid < BT) dins[tid] = 0.f;

  // Weight registers (single f16 plane of the PRE-SCALED weight):
  //   ti: 0=i (-log2e), 1=f (-log2e), 2=g (+2log2e), 3=o (-log2e)
  //   group A (layer0): WA = Whh0 ; wih0q = Wih0 rows (D-layout) ; biasq = b0
  //   group B (layer1): WA = Wih1 ; WB = Whh1 ; biasq = b1       (all scaled)
  f16x8 WA[4][2], WB[4][2];
  f32x4 biasq[4], wih0q[4];

  auto gscale = [&](int ti) { return (ti == 2) ? SCL_G : SCL_I; };

  auto cvtrow = [&](const float* p, float s, f16x8& w) {
    #pragma unroll
    for (int j = 0; j < 8; ++j) w[j] = (_Float16)(p[j] * s);
  };
  auto loadA = [&](const float* Wih0_, const float* Whh0_, const float* b0_) {
    #pragma unroll
    for (int ti = 0; ti < 4; ++ti) {
      const float s = gscale(ti);
      const int rw = (ti * 4 + wg) * 16 + n;        // weight fragment row
      const int rq = (ti * 4 + wg) * 16 + (q << 2); // D-row base for bias/wih0
      #pragma unroll
      for (int rr = 0; rr < 4; ++rr) {
        biasq[ti][rr] = b0_[rq + rr] * s;
        wih0q[ti][rr] = Wih0_[rq + rr] * s;
      }
      #pragma unroll
      for (int kc = 0; kc < 2; ++kc)
        cvtrow(Whh0_ + rw * 64 + kc * 32 + q * 8, s, WA[ti][kc]);
    }
  };
  auto loadB = [&](const float* Wih1_, const float* Whh1_, const float* b1_) {
    #pragma unroll
    for (int ti = 0; ti < 4; ++ti) {
      const float s = gscale(ti);
      const int rw = (ti * 4 + wg) * 16 + n;
      const int rq = (ti * 4 + wg) * 16 + (q << 2);
      #pragma unroll
      for (int rr = 0; rr < 4; ++rr) biasq[ti][rr] = b1_[rq + rr] * s;
      #pragma unroll
      for (int kc = 0; kc < 2; ++kc) {
        cvtrow(Wih1_ + rw * 64 + kc * 32 + q * 8, s, WA[ti][kc]);
        cvtrow(Whh1_ + rw * 64 + kc * 32 + q * 8, s, WB[ti][kc]);
      }
    }
  };

  if (wv < 4) loadA(eWih0, eWhh0, eb0);
  else        loadB(eWih1, eWhh1, eb1);

  // c-state: lane owns (batch n, hidden cbase+0..3), pairs (0,1),(2,3).
  f32x2 cp[2] = {{0.f, 0.f}, {0.f, 0.f}};

  // Packed fused activation, chain-minimized. Pre-scaled exp2 args:
  //   a0=-K*i, a1=-K*f, a2=2K*g, a3=-K*o.   ei=e^-i etc, eg=e^{2g}.
  //   c_new = sig(f)c + sig(i)tanh(g) = R1*(di*dg*c + (eg-1)*df),
  //   R1 = rcp((di*df)*dg). All of s=(di*c)*dg + fma(eg,df,-df) and
  //   sg=SCLG*s are ready before R1 lands -> post-R1 chain = mul,min,exp.
  //   out = (ec-1)*R2, R2 = rcp(fma(ec,dd,dd)).
  auto act2 = [&](f32x2 a0, f32x2 a1, f32x2 a2, f32x2 a3, f32x2& c) -> f32x2 {
    f32x2 ei, ef, eg, eo;
    ei.x = fexp2(a0.x); ei.y = fexp2(a0.y);
    ef.x = fexp2(a1.x); ef.y = fexp2(a1.y);
    eg.x = fexp2(a2.x); eg.y = fexp2(a2.y);
    eo.x = fexp2(a3.x); eo.y = fexp2(a3.y);
    const f32x2 one = {1.f, 1.f};
    f32x2 di = one + ei, df = one + ef, dg = one + eg, dd = one + eo;
    f32x2 dif = di * df;                 // ready before eg path completes
    f32x2 dic = di * c;                  // early: uses state
    f32x2 t1  = dif * dg;                // depth 2 from eg
    f32x2 nd  = eg * df - df;            // v_pk_fma(eg, df, -df) = ng*df
    f32x2 pc  = dic * dg;                // di*dg*c
    f32x2 s   = pc + nd;                 // numerator of c_new
    const f32x2 sclg = {SCL_G, SCL_G};
    f32x2 sg  = sclg * s;                // pre-scaled for ca
    f32x2 R1; R1.x = frcp(t1.x); R1.y = frcp(t1.y);
    c = R1 * s;                          // c_new: ONE op after rcp
    f32x2 ca = R1 * sg;                  // parallel with c
    const f32x2 cap = {20.f, 20.f};
    ca.x = fminf(ca.x, cap.x); ca.y = fminf(ca.y, cap.y);
    f32x2 ec; ec.x = fexp2(ca.x); ec.y = fexp2(ca.y);
    f32x2 t2 = ec * dd + dd;             // v_pk_fma: (1+ec)*dd in one level
    f32x2 nc = ec - one;                 // parallel
    f32x2 R2; R2.x = frcp(t2.x); R2.y = frcp(t2.y);
    return nc * R2;                      // sig(o)*tanh(c)
  };

  // Shared epilogue: act on 4 D-rows (2 packed pairs) + single b64 h publish
  // (4 consecutive hidden units at row n, col cbase).
  auto epilogue = [&](const f32x4* g, _Float16* O) {
    f32x2 h2[2];
    #pragma unroll
    for (int pr = 0; pr < 2; ++pr) {
      f32x2 a0 = {g[0][2 * pr], g[0][2 * pr + 1]};
      f32x2 a1 = {g[1][2 * pr], g[1][2 * pr + 1]};
      f32x2 a2 = {g[2][2 * pr], g[2][2 * pr + 1]};
      f32x2 a3 = {g[3][2 * pr], g[3][2 * pr + 1]};
      h2[pr] = act2(a0, a1, a2, a3, cp[pr]);
    }
    f16x4 hv;
    hv[0] = (_Float16)h2[0].x; hv[1] = (_Float16)h2[0].y;
    hv[2] = (_Float16)h2[1].x; hv[3] = (_Float16)h2[1].y;
    *(f16x4*)(O + nH + cbase) = hv;      // aligned 8B ds_write_b64
  };

  // layer0 step: D = bias + x(*)wih0 + Whh0 * h0^T (pre-scaled).
  auto stepA = [&](const _Float16* H, _Float16* O, float xb) {
    const _Float16* hp = H + nH;
    f16x8 a0 = *(const f16x8*)(hp + q * 8);
    f16x8 a1 = *(const f16x8*)(hp + 32 + q * 8);
    const f32x4 xbv = {xb, xb, xb, xb};
    f32x4 g[4];
    #pragma unroll
    for (int ti = 0; ti < 4; ++ti) {
      f32x4 ci = biasq[ti] + xbv * wih0q[ti];   // 2 v_pk_fma
      f32x4 a = mm1(WA[ti][0], a0, ci);
      a = mm1(WA[ti][1], a1, a);
      g[ti] = a;
    }
    epilogue(g, O);
  };

  // layer1 step: D = bias + Wih1 * h0^T + Whh1 * h1^T (pre-scaled).
  auto stepB = [&](const _Float16* H0, const _Float16* H1, _Float16* O) {
    const _Float16* p0 = H0 + nH;
    const _Float16* p1 = H1 + nH;
    f16x8 b0 = *(const f16x8*)(p0 + q * 8);
    f16x8 b1 = *(const f16x8*)(p0 + 32 + q * 8);
    f16x8 a0 = *(const f16x8*)(p1 + q * 8);
    f16x8 a1 = *(const f16x8*)(p1 + 32 + q * 8);
    f32x4 g[4];
    #pragma unroll
    for (int ti = 0; ti < 4; ++ti) {
      f32x4 a = mm1(WA[ti][0], b0, biasq[ti]);
      a = mm1(WA[ti][1], b1, a);
      a = mm1(WB[ti][0], a0, a);
      a = mm1(WB[ti][1], a1, a);
      g[ti] = a;
    }
    epilogue(g, O);
  };

  __syncthreads();

  // ---- encoder, unrolled x2 with static parity ----
  // slot s: A reads h0[(s&1)^1] writes h0[s&1];
  // B (t=s-1) reads h0[t&1], h1[(t&1)^1], writes h1[t&1].

  float xb_next;
  // s = 0 (even): A only. h0[1] is zeros.
  if (wv < 4) {
    float xb = xs[n];
    stepA(h0s[1], h0s[0], xb);
    xb_next = xs[BT + n];               // prefetch s=1 (xs read-only)
  }
  __syncthreads();

  // s = 1..364 as 182 (odd, even) pairs — both groups always active.
  for (int s = 1; s <= 363; s += 2) {
    // slot s (odd): A h0[0]->h0[1] ; B(t even) h0[0],h1[1] -> h1[0]
    if (wv < 4) {
      stepA(h0s[0], h0s[1], xb_next);
      xb_next = xs[(s + 1) * BT + n];   // prefetch s+1
    } else {
      stepB(h0s[0], h1s[1], h1s[0]);
    }
    __syncthreads();
    // slot s+1 (even): A h0[1]->h0[0] ; B(t odd) h0[1],h1[0] -> h1[1]
    if (wv < 4) {
      stepA(h0s[1], h0s[0], xb_next);
      if (s + 2 <= 364)
        xb_next = xs[(s + 2) * BT + n]; // prefetch s+2
    } else {
      stepB(h0s[1], h1s[0], h1s[1]);
    }
    __syncthreads();
  }

  // s = 365 (odd): A loads decoder weights (idle slot); B(t=364 even):
  // h0[0], h1[1] -> h1[0].
  if (wv < 4) loadA(dWih0, dWhh0, db0);
  else        stepB(h0s[0], h1s[1], h1s[0]);
  __syncthreads();

  // ---- decoder ---- (latest h0, h1 live in parity-0 buffers)
  if (wv >= 4) loadB(dWih1, dWhh1, db1);
  float fcw[16];
  #pragma unroll
  for (int j = 0; j < 16; ++j) fcw[j] = fcW[q * 16 + j];
  const float fcb0 = fcb[0];

  #pragma unroll 1
  for (int hz = 0; hz < HZ; ++hz) {
    const int p = hz & 1;           // latest state parity at step entry
    if (wv < 4) {
      stepA(h0s[p], h0s[1 - p], dins[n]);
    }
    __syncthreads();
    if (wv >= 4) {
      stepB(h0s[1 - p], h1s[p], h1s[1 - p]);
    }
    __syncthreads();
    if (wv == 0) {
      const _Float16* Hh = h1s[1 - p];
      f16x8 hh0 = *(const f16x8*)(Hh + nH + q * 16);
      f16x8 hh1 = *(const f16x8*)(Hh + nH + q * 16 + 8);
      float pacc = 0.f;
      #pragma unroll
      for (int j = 0; j < 8; ++j) pacc += fcw[j] * (float)hh0[j];
      #pragma unroll
      for (int j = 0; j < 8; ++j) pacc += fcw[8 + j] * (float)hh1[j];
      pacc += __shfl_down(pacc, 32);
      pacc += __shfl_down(pacc, 16);
      if (lane < BT) {
        pacc += fcb0;
        out[(b0g + lane) * HZ + hz] = pacc;
        dins[lane] = pacc;
      }
    }
    __syncthreads();
  }
}

extern "C" void kernel_launch(void* const* d_in, const int* in_sizes, int n_in,
                              void* d_out, int out_size, void* d_ws, size_t ws_size,
                              hipStream_t stream) {
  (void)in_sizes; (void)n_in; (void)d_ws; (void)ws_size; (void)out_size;
  const float* x     = (const float*)d_in[0];
  const float* eWih0 = (const float*)d_in[1];
  const float* eWhh0 = (const float*)d_in[2];
  const float* eb0   = (const float*)d_in[3];
  const float* eWih1 = (const float*)d_in[4];
  const float* eWhh1 = (const float*)d_in[5];
  const float* eb1   = (const float*)d_in[6];
  const float* dWih0 = (const float*)d_in[7];
  const float* dWhh0 = (const float*)d_in[8];
  const float* db0   = (const float*)d_in[9];
  const float* dWih1 = (const float*)d_in[10];
  const float* dWhh1 = (const float*)d_in[11];
  const float* db1   = (const float*)d_in[12];
  const float* fcW   = (const float*)d_in[13];
  const float* fcb   = (const float*)d_in[14];
  float* out = (float*)d_out;

  dim3 grid(4096 / BT);   // 256 blocks = 1/CU
  dim3 block(512);        // 8 waves: 4 layer0 + 4 layer1
  hipLaunchKernelGGL(lstm_fused, grid, block, 0, stream,
                     x, eWih0, eWhh0, eb0, eWih1, eWhh1, eb1,
                     dWih0, dWhh0, db0, dWih1, dWhh1, db1, fcW, fcb, out);
}